// Round 17
// baseline (273.430 us; speedup 1.0000x reference)
//
#include <hip/hip_runtime.h>
#include <math.h>

typedef __attribute__((ext_vector_type(8))) short short8;
typedef __attribute__((ext_vector_type(4))) float f32x4;
typedef __attribute__((ext_vector_type(16))) float f32x16;
typedef __attribute__((ext_vector_type(4))) unsigned short ushort4v;
typedef __attribute__((ext_vector_type(2))) unsigned short ushort2v;
typedef __attribute__((ext_vector_type(2))) int int2v;

#define AS1 __attribute__((address_space(1)))
#define AS3 __attribute__((address_space(3)))
#define GLOAD16(src, dst) __builtin_amdgcn_global_load_lds((const AS1 void*)(src), (AS3 void*)(dst), 16, 0, 0)
#define VMWAIT(N) asm volatile("s_waitcnt vmcnt(" #N ")" ::: "memory")
#define LGKM0()   asm volatile("s_waitcnt lgkmcnt(0)" ::: "memory")

__device__ __forceinline__ unsigned short f2b(float f) {
    union { float f; unsigned int u; } c; c.f = f;
    return (unsigned short)((c.u + 0x7FFFu + ((c.u >> 16) & 1u)) >> 16);
}
__device__ __forceinline__ float b2f(unsigned short u) {
    union { unsigned int u; float f; } c; c.u = ((unsigned int)u) << 16;
    return c.f;
}
__device__ __forceinline__ int cvt_pk_bf16(float a, float b) {
    int r;
    asm("v_cvt_pk_bf16_f32 %0, %1, %2" : "=v"(r) : "v"(a), "v"(b));
    return r;
}
__device__ __forceinline__ int xcd_swz(int id, int nwg) {
    int q = nwg >> 3, r = nwg & 7, x = id & 7, rest = id >> 3;
    return (x < r ? x * (q + 1) : r * (q + 1) + (x - r) * q) + rest;
}

// ---------------- fp32 -> bf16 convert: x and w_qkv into contiguous dst ----------------
__global__ void cvt2(const float* __restrict__ a, const float* __restrict__ bsrc,
                     unsigned short* __restrict__ dst, int n4a) {
    int f = blockIdx.x * 256 + threadIdx.x;
    float4 v = (f < n4a) ? ((const float4*)a)[f] : ((const float4*)bsrc)[f - n4a];
    ushort4v o;
    o.x = f2b(v.x); o.y = f2b(v.y); o.z = f2b(v.z); o.w = f2b(v.w);
    ((ushort4v*)dst)[f] = o;
}

// ---------------- fused mid: rope (vectorized) + vtrans (short2 stores) + cvt w_proj ------
// grid: 4096 (rope) + 2048 (vtrans) + 1024 (cvt w_proj) = 7168 blocks
__global__ __launch_bounds__(256) void mid_fused(unsigned short* __restrict__ qkv,
                                                 unsigned short* __restrict__ vtg,
                                                 const float* __restrict__ wproj,
                                                 unsigned short* __restrict__ wpb) {
    int bid = blockIdx.x;
    if (bid < 4096) {                        // rope: B*T*H*16 threads, 4 elems each
        int tid = bid * 256 + threadIdx.x;
        int i4 = (tid & 15) << 2;            // 0,4,...,60
        int h = (tid >> 4) & 15;
        int t = (tid >> 8) & 2047;
        int b = tid >> 19;
        size_t base0 = ((size_t)(((b << 11) + t) * 3)) << 11;
#pragma unroll
        for (int s = 0; s < 2; ++s) {
            size_t base = base0 + (size_t)s * 2048 + (h << 7);
            ushort4v v1 = *(const ushort4v*)(qkv + base + i4);
            ushort4v v2 = *(const ushort4v*)(qkv + base + 64 + i4);
            ushort4v o1, o2;
#pragma unroll
            for (int j = 0; j < 4; ++j) {
                int i = i4 + j;
                float inv = __expf((float)i * -0.14391156608f);
                float ang = (float)t * inv;
                float sn = sinf(ang), cs = cosf(ang);
                float a1 = b2f(v1[j]), a2 = b2f(v2[j]);
                o1[j] = f2b(a1 * cs - a2 * sn);
                o2[j] = f2b(a2 * cs + a1 * sn);
            }
            *(ushort4v*)(qkv + base + i4) = o1;
            *(ushort4v*)(qkv + base + 64 + i4) = o2;
        }
    } else if (bid < 4096 + 2048) {          // vtrans: 2 t-columns per thread
        int flat = (bid - 4096) * 256 + threadIdx.x;   // [b][h][dc][t2]
        int t2 = flat & 1023;
        int dc = (flat >> 10) & 15;
        int h = (flat >> 14) & 15;
        int b = flat >> 18;
        int t = t2 << 1;
        const unsigned short* src = qkv + ((size_t)(b * 2048 + t) * 3 + 2) * 2048 + h * 128 + dc * 8;
        short8 v0 = *(const short8*)src;
        short8 v1 = *(const short8*)(src + 3 * 2048);
        size_t base = ((size_t)(b * 16 + h) * 128 + dc * 8) * 2048 + t;
#pragma unroll
        for (int j = 0; j < 8; j++) {
            ushort2v o; o[0] = (unsigned short)v0[j]; o[1] = (unsigned short)v1[j];
            *(ushort2v*)(vtg + base + (size_t)j * 2048) = o;
        }
    } else {                                 // cvt w_proj
        int f = (bid - 6144) * 256 + threadIdx.x;
#pragma unroll
        for (int r = 0; r < 4; ++r, f += 1024 * 256) {
            float4 v = ((const float4*)wproj)[f];
            ushort4v o;
            o.x = f2b(v.x); o.y = f2b(v.y); o.z = f2b(v.z); o.w = f2b(v.w);
            ((ushort4v*)wpb)[f] = o;
        }
    }
}

// ---------------- bf16 NT GEMM, 3-slot ring (R13/R16, verified): C = A * B^T --------------
template<int OUT_BF16>
__global__ __launch_bounds__(512, 2) void gemm_nt(const unsigned short* __restrict__ A,
                                                  const unsigned short* __restrict__ B,
                                                  void* __restrict__ Cout,
                                                  int N, int K) {
    __shared__ __attribute__((aligned(16))) char lds[73728];
    int tid = threadIdx.x, lane = tid & 63, w = tid >> 6;
    int col = lane & 15, lg = lane >> 4;
    int wr = w >> 2, wc = w & 3;
    int gx = gridDim.x;
    int nwg = gx * gridDim.y;
    int id = xcd_swz(blockIdx.y * gx + blockIdx.x, nwg);
    int rowBase = (id / gx) * 128;
    int colBase = (id % gx) * 256;
    int nkt = K >> 5;

    f32x4 acc[4][4];
#pragma unroll
    for (int m = 0; m < 4; m++)
#pragma unroll
        for (int n = 0; n < 4; n++) acc[m][n] = (f32x4){0.f, 0.f, 0.f, 0.f};

    auto slotOf = [&](int t) { return t - (t / 3) * 3; };   // t % 3

    auto stageA = [&](int t) {               // 8 KB: one gload round
        char* dst = lds + slotOf(t) * 8192 + w * 1024;      // wave-uniform base
        int u = w * 64 + lane;
        int row = u >> 2, ch = u & 3;
        const char* src = (const char*)A + ((size_t)(rowBase + row) * K + t * 32) * 2
                          + (((ch ^ (row >> 1)) & 3) << 4);
        GLOAD16(src, dst);
    };
    auto stageB = [&](int t) {               // 16 KB: two gload rounds
        char* base = lds + 24576 + slotOf(t) * 16384;
#pragma unroll
        for (int j = 0; j < 2; ++j) {
            int u = j * 512 + w * 64 + lane;
            int row = u >> 2, ch = u & 3;
            const char* src = (const char*)B + ((size_t)(colBase + row) * K + t * 32) * 2
                              + (((ch ^ (row >> 1)) & 3) << 4);
            GLOAD16(src, base + j * 8192 + w * 1024);
        }
    };

    // prologue: tiles 0,1 in flight (6 gloads/thread)
    stageA(0); stageB(0); stageA(1); stageB(1);

    for (int t = 0; t < nkt; ++t) {
        if (t + 1 < nkt) VMWAIT(3);          // tile t retired; t+1 stays in flight
        else             VMWAIT(0);
        __builtin_amdgcn_s_barrier();        // all waves' tile-t quarters visible
        if (t + 2 < nkt) { stageA(t + 2); stageB(t + 2); }  // slot t-1: dead since barrier
        const char* Ab = lds + slotOf(t) * 8192;
        const char* Bb = lds + 24576 + slotOf(t) * 16384;
        short8 af[4], bf[4];
#pragma unroll
        for (int m = 0; m < 4; ++m) {
            int row = wr * 64 + m * 16 + col;
            af[m] = *(const short8*)(Ab + row * 64 + (((lg ^ (row >> 1)) & 3) << 4));
        }
#pragma unroll
        for (int n = 0; n < 4; ++n) {
            int row = wc * 64 + n * 16 + col;
            bf[n] = *(const short8*)(Bb + row * 64 + (((lg ^ (row >> 1)) & 3) << 4));
        }
        __builtin_amdgcn_s_setprio(1);
#pragma unroll
        for (int m = 0; m < 4; ++m)
#pragma unroll
            for (int n = 0; n < 4; ++n)
                acc[m][n] = __builtin_amdgcn_mfma_f32_16x16x32_bf16(af[m], bf[n], acc[m][n], 0, 0, 0);
        __builtin_amdgcn_s_setprio(0);
        LGKM0();                              // reads retired before next barrier
    }

    int rbase = 4 * lg;
#pragma unroll
    for (int m = 0; m < 4; m++)
#pragma unroll
        for (int reg = 0; reg < 4; ++reg) {
            int r = rowBase + wr * 64 + m * 16 + rbase + reg;
#pragma unroll
            for (int n = 0; n < 4; n++) {
                int c = colBase + wc * 64 + n * 16 + col;
                float v = acc[m][n][reg];
                if (OUT_BF16) ((unsigned short*)Cout)[(size_t)r * N + c] = f2b(v);
                else          ((float*)Cout)[(size_t)r * N + c] = v;
            }
        }
}

// ---------------- fused causal flash attention (R11 structure + tree reductions) ----------
__global__ __launch_bounds__(256, 2) void attn_fused(const unsigned short* __restrict__ qkv,
                                                     const unsigned short* __restrict__ vtg,
                                                     unsigned short* __restrict__ out) {
    constexpr int T = 2048;
    __shared__ unsigned short Kl[2][64 * 128];   // 32 KB: [kv][256B rows], XOR-swizzled
    __shared__ unsigned short Vl[2][128 * 64];   // 32 KB: [d][128B rows], XOR-swizzled
    int tid = threadIdx.x, lane = tid & 63, w = tid >> 6;
    int q = lane & 31, hi = lane >> 5;
    int id = blockIdx.x;
    int bh = id & 31;
    int u = (id >> 5) & 7;
    int qt = (id >> 8) ? (15 - u) : u;      // in [0,16)
    int b = bh >> 4, h = bh & 15;
    const float sc2 = 0.08838834764831845f * 1.44269504088896340f;  // 1/sqrt(128)*log2(e)

    int qbase = qt * 128;
    int nkv = 2 * qt + 2;
    int tq = qbase + w * 32 + q;

    auto stageK = [&](int t) {
        int kvb = t * 64;
        char* Kb = (char*)&Kl[t & 1][0];
#pragma unroll
        for (int it = 0; it < 4; ++it) {
            int dby = it * 4096 + tid * 16;
            int row = dby >> 8, cb = dby & 255;
            int scb = cb ^ ((row & 7) << 4);
            const char* src = (const char*)qkv + (((size_t)(b * T + kvb + row) * 3 + 1) * 2048 + h * 128) * 2 + scb;
            GLOAD16(src, Kb + it * 4096 + w * 1024);
        }
    };
    auto stageV = [&](int t) {
        int kvb = t * 64;
        char* Vb = (char*)&Vl[t & 1][0];
#pragma unroll
        for (int it = 0; it < 4; ++it) {
            int dby = it * 4096 + tid * 16;
            int d = dby >> 7, cb = dby & 127;
            int scb = cb ^ ((d & 7) << 4);
            const char* src = (const char*)vtg + (((size_t)bh * 128 + d) * 2048 + kvb) * 2 + scb;
            GLOAD16(src, Vb + it * 4096 + w * 1024);
        }
    };

    // issue first K/V stage BEFORE Q-register loads (qf retires under the same VMWAIT(8))
    stageK(0); stageV(0);

    short8 qf[8];
    {
        const unsigned short* qp = qkv + ((size_t)(b * T + tq) * 3) * 2048 + h * 128;
#pragma unroll
        for (int s = 0; s < 8; s++) qf[s] = *(const short8*)(qp + s * 16 + hi * 8);
    }
    f32x16 O[4];
#pragma unroll
    for (int dt = 0; dt < 4; dt++)
#pragma unroll
        for (int r = 0; r < 16; r++) O[dt][r] = 0.f;
    float m = -1e30f, l = 0.f;

    for (int kv = 0; kv < nkv; ++kv) {
        if (kv + 1 < nkv) {
            stageK(kv + 1);
            stageV(kv + 1);
            VMWAIT(8);
        } else {
            VMWAIT(0);
        }
        __builtin_amdgcn_s_barrier();
        int kvbase = kv * 64;
        bool act = kvbase < qbase + (w + 1) * 32;
        const char* Kb = (const char*)&Kl[kv & 1][0];
        const char* Vb = (const char*)&Vl[kv & 1][0];
        if (act) {
            f32x16 p0, p1;
#pragma unroll
            for (int r = 0; r < 16; r++) { p0[r] = 0.f; p1[r] = 0.f; }
            __builtin_amdgcn_s_setprio(1);
#pragma unroll
            for (int s = 0; s < 8; s++) {
                int cb = s * 32 + hi * 16;
                short8 k0 = *(const short8*)(Kb + q * 256 + (cb ^ ((q & 7) << 4)));
                p0 = __builtin_amdgcn_mfma_f32_32x32x16_bf16(k0, qf[s], p0, 0, 0, 0);
                short8 k1 = *(const short8*)(Kb + (32 + q) * 256 + (cb ^ ((q & 7) << 4)));
                p1 = __builtin_amdgcn_mfma_f32_32x32x16_bf16(k1, qf[s], p1, 0, 0, 0);
            }
            __builtin_amdgcn_s_setprio(0);
#pragma unroll
            for (int r = 0; r < 16; r++) { p0[r] *= sc2; p1[r] *= sc2; }
            bool diag = (kvbase + 63 > qbase + w * 32);
            if (diag) {
#pragma unroll
                for (int r = 0; r < 16; r++) {
                    int kg = kvbase + (r & 3) + 8 * (r >> 2) + 4 * hi;
                    if (kg > tq) p0[r] = -3e38f;
                    if (kg + 32 > tq) p1[r] = -3e38f;
                }
            }
            // online softmax: tree max (depth 5) instead of serial chain
            float tr[16];
#pragma unroll
            for (int r = 0; r < 16; r++) tr[r] = fmaxf(p0[r], p1[r]);
#pragma unroll
            for (int r = 0; r < 8; r++) tr[r] = fmaxf(tr[r], tr[r + 8]);
#pragma unroll
            for (int r = 0; r < 4; r++) tr[r] = fmaxf(tr[r], tr[r + 4]);
            float mx = fmaxf(fmaxf(tr[0], tr[1]), fmaxf(tr[2], tr[3]));
            mx = fmaxf(mx, __shfl_xor(mx, 32));
            if (!__all(mx - m <= 8.0f)) {   // defer-max (T13)
                float mn = fmaxf(m, mx);
                float esc = exp2f(m - mn);
                m = mn;
                l *= esc;
#pragma unroll
                for (int dt = 0; dt < 4; dt++)
#pragma unroll
                    for (int r = 0; r < 16; r++) O[dt][r] *= esc;
            }
            // exp2 + 4-way partial sums (shorter dependence chains)
            float s0 = 0.f, s1 = 0.f, s2 = 0.f, s3 = 0.f;
#pragma unroll
            for (int r = 0; r < 16; r += 4) {
                p0[r]     = exp2f(p0[r]     - m); s0 += p0[r];
                p0[r + 1] = exp2f(p0[r + 1] - m); s1 += p0[r + 1];
                p0[r + 2] = exp2f(p0[r + 2] - m); s2 += p0[r + 2];
                p0[r + 3] = exp2f(p0[r + 3] - m); s3 += p0[r + 3];
                p1[r]     = exp2f(p1[r]     - m); s0 += p1[r];
                p1[r + 1] = exp2f(p1[r + 1] - m); s1 += p1[r + 1];
                p1[r + 2] = exp2f(p1[r + 2] - m); s2 += p1[r + 2];
                p1[r + 3] = exp2f(p1[r + 3] - m); s3 += p1[r + 3];
            }
            float rs = (s0 + s1) + (s2 + s3);
            rs += __shfl_xor(rs, 32);
            l += rs;
            // PA fragments (B-operand of PV)
            union Frag { int i[4]; short8 s; } pa[4];
#pragma unroll
            for (int g = 0; g < 4; g++) {
                float e[8];
#pragma unroll
                for (int j = 0; j < 8; j++) e[j] = (g < 2) ? p0[(g & 1) * 8 + j] : p1[(g & 1) * 8 + j];
                int a0 = cvt_pk_bf16(e[0], e[1]);
                int a1 = cvt_pk_bf16(e[2], e[3]);
                int b0 = cvt_pk_bf16(e[4], e[5]);
                int b1 = cvt_pk_bf16(e[6], e[7]);
                int s0i = hi ? a0 : b0; int r0 = __shfl_xor(s0i, 32);
                int s1i = hi ? a1 : b1; int r1 = __shfl_xor(s1i, 32);
                pa[g].i[0] = hi ? r0 : a0;
                pa[g].i[1] = hi ? r1 : a1;
                pa[g].i[2] = hi ? b0 : r0;
                pa[g].i[3] = hi ? b1 : r1;
            }
            __builtin_amdgcn_s_setprio(1);
#pragma unroll
            for (int dt = 0; dt < 4; dt++) {
                int d = dt * 32 + q;
#pragma unroll
                for (int ks = 0; ks < 4; ks++) {
                    short8 vfr = *(const short8*)(Vb + d * 128 + ((ks * 32 + hi * 16) ^ ((d & 7) << 4)));
                    O[dt] = __builtin_amdgcn_mfma_f32_32x32x16_bf16(vfr, pa[ks].s, O[dt], 0, 0, 0);
                }
            }
            __builtin_amdgcn_s_setprio(0);
        }
        LGKM0();
        __builtin_amdgcn_s_barrier();
    }
    float linv = 1.0f / l;
    size_t obase = ((size_t)bh * T + tq) * 128;
#pragma unroll
    for (int dt = 0; dt < 4; dt++)
#pragma unroll
        for (int g = 0; g < 4; g++) {
            int d0 = dt * 32 + g * 8 + 4 * hi;
            int w0 = cvt_pk_bf16(O[dt][4 * g + 0] * linv, O[dt][4 * g + 1] * linv);
            int w1 = cvt_pk_bf16(O[dt][4 * g + 2] * linv, O[dt][4 * g + 3] * linv);
            int2v o; o[0] = w0; o[1] = w1;
            *(int2v*)(out + obase + d0) = o;
        }
}

// ---------------- launch ----------------
extern "C" void kernel_launch(void* const* d_in, const int* in_sizes, int n_in,
                              void* d_out, int out_size, void* d_ws, size_t ws_size,
                              hipStream_t stream) {
    const float* x      = (const float*)d_in[0];
    const float* w_qkv  = (const float*)d_in[1];
    const float* w_proj = (const float*)d_in[2];
    const int B = 2, T = 2048, C = 2048;
    const int M = B * T;        // 4096
    const int F = 3 * C;        // 6144

    size_t need = ((size_t)M * C + (size_t)F * C + (size_t)M * F) * 2;
    if (ws_size < need) return;
    unsigned short* rX  = (unsigned short*)d_ws;            // x bf16, later attn-out
    unsigned short* rW  = rX + (size_t)M * C;               // w_qkv bf16, later VT + w_proj
    unsigned short* rQ  = rW + (size_t)F * C;               // qkv
    unsigned short* rVT = rW;
    unsigned short* rWp = rW + (size_t)B * 16 * 128 * T;

    cvt2<<<(M * C + F * C) / 1024, 256, 0, stream>>>(x, w_qkv, rX, (M * C) / 4);
    gemm_nt<1><<<dim3(F / 256, M / 128), 512, 0, stream>>>(rX, rW, (void*)rQ, F, C);
    mid_fused<<<4096 + 2048 + 1024, 256, 0, stream>>>(rQ, rVT, w_proj, rWp);
    attn_fused<<<512, 256, 0, stream>>>(rQ, rVT, rX);
    gemm_nt<0><<<dim3(C / 256, M / 128), 512, 0, stream>>>(rX, rWp, d_out, C, C);
}

// Round 18
// 267.838 us; speedup vs baseline: 1.0209x; 1.0209x over previous
//
#include <hip/hip_runtime.h>
#include <math.h>

typedef __attribute__((ext_vector_type(8))) short short8;
typedef __attribute__((ext_vector_type(4))) float f32x4;
typedef __attribute__((ext_vector_type(16))) float f32x16;
typedef __attribute__((ext_vector_type(4))) unsigned short ushort4v;
typedef __attribute__((ext_vector_type(2))) unsigned short ushort2v;
typedef __attribute__((ext_vector_type(2))) int int2v;

#define AS1 __attribute__((address_space(1)))
#define AS3 __attribute__((address_space(3)))
#define GLOAD16(src, dst) __builtin_amdgcn_global_load_lds((const AS1 void*)(src), (AS3 void*)(dst), 16, 0, 0)
#define VMWAIT(N) asm volatile("s_waitcnt vmcnt(" #N ")" ::: "memory")
#define LGKM0()   asm volatile("s_waitcnt lgkmcnt(0)" ::: "memory")

__device__ __forceinline__ unsigned short f2b(float f) {
    union { float f; unsigned int u; } c; c.f = f;
    return (unsigned short)((c.u + 0x7FFFu + ((c.u >> 16) & 1u)) >> 16);
}
__device__ __forceinline__ float b2f(unsigned short u) {
    union { unsigned int u; float f; } c; c.u = ((unsigned int)u) << 16;
    return c.f;
}
__device__ __forceinline__ int cvt_pk_bf16(float a, float b) {
    int r;
    asm("v_cvt_pk_bf16_f32 %0, %1, %2" : "=v"(r) : "v"(a), "v"(b));
    return r;
}
__device__ __forceinline__ int xcd_swz(int id, int nwg) {
    int q = nwg >> 3, r = nwg & 7, x = id & 7, rest = id >> 3;
    return (x < r ? x * (q + 1) : r * (q + 1) + (x - r) * q) + rest;
}

// ---------------- fp32 -> bf16 convert: x and w_qkv into contiguous dst ----------------
__global__ void cvt2(const float* __restrict__ a, const float* __restrict__ bsrc,
                     unsigned short* __restrict__ dst, int n4a) {
    int f = blockIdx.x * 256 + threadIdx.x;
    float4 v = (f < n4a) ? ((const float4*)a)[f] : ((const float4*)bsrc)[f - n4a];
    ushort4v o;
    o.x = f2b(v.x); o.y = f2b(v.y); o.z = f2b(v.z); o.w = f2b(v.w);
    ((ushort4v*)dst)[f] = o;
}

// ---------------- fused mid: rope (vectorized) + vtrans (short2 stores) + cvt w_proj ------
__global__ __launch_bounds__(256) void mid_fused(unsigned short* __restrict__ qkv,
                                                 unsigned short* __restrict__ vtg,
                                                 const float* __restrict__ wproj,
                                                 unsigned short* __restrict__ wpb) {
    int bid = blockIdx.x;
    if (bid < 4096) {                        // rope: B*T*H*16 threads, 4 elems each
        int tid = bid * 256 + threadIdx.x;
        int i4 = (tid & 15) << 2;
        int h = (tid >> 4) & 15;
        int t = (tid >> 8) & 2047;
        int b = tid >> 19;
        size_t base0 = ((size_t)(((b << 11) + t) * 3)) << 11;
#pragma unroll
        for (int s = 0; s < 2; ++s) {
            size_t base = base0 + (size_t)s * 2048 + (h << 7);
            ushort4v v1 = *(const ushort4v*)(qkv + base + i4);
            ushort4v v2 = *(const ushort4v*)(qkv + base + 64 + i4);
            ushort4v o1, o2;
#pragma unroll
            for (int j = 0; j < 4; ++j) {
                int i = i4 + j;
                float inv = __expf((float)i * -0.14391156608f);
                float ang = (float)t * inv;
                float sn = sinf(ang), cs = cosf(ang);
                float a1 = b2f(v1[j]), a2 = b2f(v2[j]);
                o1[j] = f2b(a1 * cs - a2 * sn);
                o2[j] = f2b(a2 * cs + a1 * sn);
            }
            *(ushort4v*)(qkv + base + i4) = o1;
            *(ushort4v*)(qkv + base + 64 + i4) = o2;
        }
    } else if (bid < 4096 + 2048) {          // vtrans: 2 t-columns per thread
        int flat = (bid - 4096) * 256 + threadIdx.x;
        int t2 = flat & 1023;
        int dc = (flat >> 10) & 15;
        int h = (flat >> 14) & 15;
        int b = flat >> 18;
        int t = t2 << 1;
        const unsigned short* src = qkv + ((size_t)(b * 2048 + t) * 3 + 2) * 2048 + h * 128 + dc * 8;
        short8 v0 = *(const short8*)src;
        short8 v1 = *(const short8*)(src + 3 * 2048);
        size_t base = ((size_t)(b * 16 + h) * 128 + dc * 8) * 2048 + t;
#pragma unroll
        for (int j = 0; j < 8; j++) {
            ushort2v o; o[0] = (unsigned short)v0[j]; o[1] = (unsigned short)v1[j];
            *(ushort2v*)(vtg + base + (size_t)j * 2048) = o;
        }
    } else {                                 // cvt w_proj
        int f = (bid - 6144) * 256 + threadIdx.x;
#pragma unroll
        for (int r = 0; r < 4; ++r, f += 1024 * 256) {
            float4 v = ((const float4*)wproj)[f];
            ushort4v o;
            o.x = f2b(v.x); o.y = f2b(v.y); o.z = f2b(v.z); o.w = f2b(v.w);
            ((ushort4v*)wpb)[f] = o;
        }
    }
}

// ---------------- bf16 NT GEMM, 3-slot ring + column-major block id -----------------------
// BM=128, BN=256, BK=32; 8 waves (2x4), 512 threads. LDS ring = 3 slots, 72 KiB.
// Block id COLUMN-MAJOR (M fast): rowBase = (id % gy)*128, colBase = (id / gy)*256.
// Each XCD's contiguous id-chunk then covers few N-columns x many M-rows: its
// B working set (~3 panels = 3 MB) fits the 4 MB XCD L2 and is fetched once,
// instead of 24 thrashing panels under the old row-major id.
template<int OUT_BF16>
__global__ __launch_bounds__(512, 2) void gemm_nt(const unsigned short* __restrict__ A,
                                                  const unsigned short* __restrict__ B,
                                                  void* __restrict__ Cout,
                                                  int N, int K) {
    __shared__ __attribute__((aligned(16))) char lds[73728];
    int tid = threadIdx.x, lane = tid & 63, w = tid >> 6;
    int col = lane & 15, lg = lane >> 4;
    int wr = w >> 2, wc = w & 3;
    int gx = gridDim.x, gy = gridDim.y;
    int nwg = gx * gy;
    int id = xcd_swz(blockIdx.y * gx + blockIdx.x, nwg);
    int rowBase = (id % gy) * 128;           // M fast within an XCD chunk
    int colBase = (id / gy) * 256;
    int nkt = K >> 5;

    f32x4 acc[4][4];
#pragma unroll
    for (int m = 0; m < 4; m++)
#pragma unroll
        for (int n = 0; n < 4; n++) acc[m][n] = (f32x4){0.f, 0.f, 0.f, 0.f};

    auto slotOf = [&](int t) { return t - (t / 3) * 3; };   // t % 3

    auto stageA = [&](int t) {               // 8 KB: one gload round
        char* dst = lds + slotOf(t) * 8192 + w * 1024;
        int u = w * 64 + lane;
        int row = u >> 2, ch = u & 3;
        const char* src = (const char*)A + ((size_t)(rowBase + row) * K + t * 32) * 2
                          + (((ch ^ (row >> 1)) & 3) << 4);
        GLOAD16(src, dst);
    };
    auto stageB = [&](int t) {               // 16 KB: two gload rounds
        char* base = lds + 24576 + slotOf(t) * 16384;
#pragma unroll
        for (int j = 0; j < 2; ++j) {
            int u = j * 512 + w * 64 + lane;
            int row = u >> 2, ch = u & 3;
            const char* src = (const char*)B + ((size_t)(colBase + row) * K + t * 32) * 2
                              + (((ch ^ (row >> 1)) & 3) << 4);
            GLOAD16(src, base + j * 8192 + w * 1024);
        }
    };

    // prologue: tiles 0,1 in flight (6 gloads/thread)
    stageA(0); stageB(0); stageA(1); stageB(1);

    for (int t = 0; t < nkt; ++t) {
        if (t + 1 < nkt) VMWAIT(3);          // tile t retired; t+1 stays in flight
        else             VMWAIT(0);
        __builtin_amdgcn_s_barrier();        // all waves' tile-t quarters visible
        if (t + 2 < nkt) { stageA(t + 2); stageB(t + 2); }  // slot t-1: dead since barrier
        const char* Ab = lds + slotOf(t) * 8192;
        const char* Bb = lds + 24576 + slotOf(t) * 16384;
        short8 af[4], bf[4];
#pragma unroll
        for (int m = 0; m < 4; ++m) {
            int row = wr * 64 + m * 16 + col;
            af[m] = *(const short8*)(Ab + row * 64 + (((lg ^ (row >> 1)) & 3) << 4));
        }
#pragma unroll
        for (int n = 0; n < 4; ++n) {
            int row = wc * 64 + n * 16 + col;
            bf[n] = *(const short8*)(Bb + row * 64 + (((lg ^ (row >> 1)) & 3) << 4));
        }
        __builtin_amdgcn_s_setprio(1);
#pragma unroll
        for (int m = 0; m < 4; ++m)
#pragma unroll
            for (int n = 0; n < 4; ++n)
                acc[m][n] = __builtin_amdgcn_mfma_f32_16x16x32_bf16(af[m], bf[n], acc[m][n], 0, 0, 0);
        __builtin_amdgcn_s_setprio(0);
        LGKM0();                              // reads retired before next barrier
    }

    int rbase = 4 * lg;
#pragma unroll
    for (int m = 0; m < 4; m++)
#pragma unroll
        for (int reg = 0; reg < 4; ++reg) {
            int r = rowBase + wr * 64 + m * 16 + rbase + reg;
#pragma unroll
            for (int n = 0; n < 4; n++) {
                int c = colBase + wc * 64 + n * 16 + col;
                float v = acc[m][n][reg];
                if (OUT_BF16) ((unsigned short*)Cout)[(size_t)r * N + c] = f2b(v);
                else          ((float*)Cout)[(size_t)r * N + c] = v;
            }
        }
}

// ---------------- fused causal flash attention (R17, passing) -----------------------------
__global__ __launch_bounds__(256, 2) void attn_fused(const unsigned short* __restrict__ qkv,
                                                     const unsigned short* __restrict__ vtg,
                                                     unsigned short* __restrict__ out) {
    constexpr int T = 2048;
    __shared__ unsigned short Kl[2][64 * 128];   // 32 KB: [kv][256B rows], XOR-swizzled
    __shared__ unsigned short Vl[2][128 * 64];   // 32 KB: [d][128B rows], XOR-swizzled
    int tid = threadIdx.x, lane = tid & 63, w = tid >> 6;
    int q = lane & 31, hi = lane >> 5;
    int id = blockIdx.x;
    int bh = id & 31;
    int u = (id >> 5) & 7;
    int qt = (id >> 8) ? (15 - u) : u;      // in [0,16)
    int b = bh >> 4, h = bh & 15;
    const float sc2 = 0.08838834764831845f * 1.44269504088896340f;  // 1/sqrt(128)*log2(e)

    int qbase = qt * 128;
    int nkv = 2 * qt + 2;
    int tq = qbase + w * 32 + q;

    auto stageK = [&](int t) {
        int kvb = t * 64;
        char* Kb = (char*)&Kl[t & 1][0];
#pragma unroll
        for (int it = 0; it < 4; ++it) {
            int dby = it * 4096 + tid * 16;
            int row = dby >> 8, cb = dby & 255;
            int scb = cb ^ ((row & 7) << 4);
            const char* src = (const char*)qkv + (((size_t)(b * T + kvb + row) * 3 + 1) * 2048 + h * 128) * 2 + scb;
            GLOAD16(src, Kb + it * 4096 + w * 1024);
        }
    };
    auto stageV = [&](int t) {
        int kvb = t * 64;
        char* Vb = (char*)&Vl[t & 1][0];
#pragma unroll
        for (int it = 0; it < 4; ++it) {
            int dby = it * 4096 + tid * 16;
            int d = dby >> 7, cb = dby & 127;
            int scb = cb ^ ((d & 7) << 4);
            const char* src = (const char*)vtg + (((size_t)bh * 128 + d) * 2048 + kvb) * 2 + scb;
            GLOAD16(src, Vb + it * 4096 + w * 1024);
        }
    };

    stageK(0); stageV(0);

    short8 qf[8];
    {
        const unsigned short* qp = qkv + ((size_t)(b * T + tq) * 3) * 2048 + h * 128;
#pragma unroll
        for (int s = 0; s < 8; s++) qf[s] = *(const short8*)(qp + s * 16 + hi * 8);
    }
    f32x16 O[4];
#pragma unroll
    for (int dt = 0; dt < 4; dt++)
#pragma unroll
        for (int r = 0; r < 16; r++) O[dt][r] = 0.f;
    float m = -1e30f, l = 0.f;

    for (int kv = 0; kv < nkv; ++kv) {
        if (kv + 1 < nkv) {
            stageK(kv + 1);
            stageV(kv + 1);
            VMWAIT(8);
        } else {
            VMWAIT(0);
        }
        __builtin_amdgcn_s_barrier();
        int kvbase = kv * 64;
        bool act = kvbase < qbase + (w + 1) * 32;
        const char* Kb = (const char*)&Kl[kv & 1][0];
        const char* Vb = (const char*)&Vl[kv & 1][0];
        if (act) {
            f32x16 p0, p1;
#pragma unroll
            for (int r = 0; r < 16; r++) { p0[r] = 0.f; p1[r] = 0.f; }
            __builtin_amdgcn_s_setprio(1);
#pragma unroll
            for (int s = 0; s < 8; s++) {
                int cb = s * 32 + hi * 16;
                short8 k0 = *(const short8*)(Kb + q * 256 + (cb ^ ((q & 7) << 4)));
                p0 = __builtin_amdgcn_mfma_f32_32x32x16_bf16(k0, qf[s], p0, 0, 0, 0);
                short8 k1 = *(const short8*)(Kb + (32 + q) * 256 + (cb ^ ((q & 7) << 4)));
                p1 = __builtin_amdgcn_mfma_f32_32x32x16_bf16(k1, qf[s], p1, 0, 0, 0);
            }
            __builtin_amdgcn_s_setprio(0);
#pragma unroll
            for (int r = 0; r < 16; r++) { p0[r] *= sc2; p1[r] *= sc2; }
            bool diag = (kvbase + 63 > qbase + w * 32);
            if (diag) {
#pragma unroll
                for (int r = 0; r < 16; r++) {
                    int kg = kvbase + (r & 3) + 8 * (r >> 2) + 4 * hi;
                    if (kg > tq) p0[r] = -3e38f;
                    if (kg + 32 > tq) p1[r] = -3e38f;
                }
            }
            float tr[16];
#pragma unroll
            for (int r = 0; r < 16; r++) tr[r] = fmaxf(p0[r], p1[r]);
#pragma unroll
            for (int r = 0; r < 8; r++) tr[r] = fmaxf(tr[r], tr[r + 8]);
#pragma unroll
            for (int r = 0; r < 4; r++) tr[r] = fmaxf(tr[r], tr[r + 4]);
            float mx = fmaxf(fmaxf(tr[0], tr[1]), fmaxf(tr[2], tr[3]));
            mx = fmaxf(mx, __shfl_xor(mx, 32));
            if (!__all(mx - m <= 8.0f)) {   // defer-max (T13)
                float mn = fmaxf(m, mx);
                float esc = exp2f(m - mn);
                m = mn;
                l *= esc;
#pragma unroll
                for (int dt = 0; dt < 4; dt++)
#pragma unroll
                    for (int r = 0; r < 16; r++) O[dt][r] *= esc;
            }
            float s0 = 0.f, s1 = 0.f, s2 = 0.f, s3 = 0.f;
#pragma unroll
            for (int r = 0; r < 16; r += 4) {
                p0[r]     = exp2f(p0[r]     - m); s0 += p0[r];
                p0[r + 1] = exp2f(p0[r + 1] - m); s1 += p0[r + 1];
                p0[r + 2] = exp2f(p0[r + 2] - m); s2 += p0[r + 2];
                p0[r + 3] = exp2f(p0[r + 3] - m); s3 += p0[r + 3];
                p1[r]     = exp2f(p1[r]     - m); s0 += p1[r];
                p1[r + 1] = exp2f(p1[r + 1] - m); s1 += p1[r + 1];
                p1[r + 2] = exp2f(p1[r + 2] - m); s2 += p1[r + 2];
                p1[r + 3] = exp2f(p1[r + 3] - m); s3 += p1[r + 3];
            }
            float rs = (s0 + s1) + (s2 + s3);
            rs += __shfl_xor(rs, 32);
            l += rs;
            union Frag { int i[4]; short8 s; } pa[4];
#pragma unroll
            for (int g = 0; g < 4; g++) {
                float e[8];
#pragma unroll
                for (int j = 0; j < 8; j++) e[j] = (g < 2) ? p0[(g & 1) * 8 + j] : p1[(g & 1) * 8 + j];
                int a0 = cvt_pk_bf16(e[0], e[1]);
                int a1 = cvt_pk_bf16(e[2], e[3]);
                int b0 = cvt_pk_bf16(e[4], e[5]);
                int b1 = cvt_pk_bf16(e[6], e[7]);
                int s0i = hi ? a0 : b0; int r0 = __shfl_xor(s0i, 32);
                int s1i = hi ? a1 : b1; int r1 = __shfl_xor(s1i, 32);
                pa[g].i[0] = hi ? r0 : a0;
                pa[g].i[1] = hi ? r1 : a1;
                pa[g].i[2] = hi ? b0 : r0;
                pa[g].i[3] = hi ? b1 : r1;
            }
            __builtin_amdgcn_s_setprio(1);
#pragma unroll
            for (int dt = 0; dt < 4; dt++) {
                int d = dt * 32 + q;
#pragma unroll
                for (int ks = 0; ks < 4; ks++) {
                    short8 vfr = *(const short8*)(Vb + d * 128 + ((ks * 32 + hi * 16) ^ ((d & 7) << 4)));
                    O[dt] = __builtin_amdgcn_mfma_f32_32x32x16_bf16(vfr, pa[ks].s, O[dt], 0, 0, 0);
                }
            }
            __builtin_amdgcn_s_setprio(0);
        }
        LGKM0();
        __builtin_amdgcn_s_barrier();
    }
    float linv = 1.0f / l;
    size_t obase = ((size_t)bh * T + tq) * 128;
#pragma unroll
    for (int dt = 0; dt < 4; dt++)
#pragma unroll
        for (int g = 0; g < 4; g++) {
            int d0 = dt * 32 + g * 8 + 4 * hi;
            int w0 = cvt_pk_bf16(O[dt][4 * g + 0] * linv, O[dt][4 * g + 1] * linv);
            int w1 = cvt_pk_bf16(O[dt][4 * g + 2] * linv, O[dt][4 * g + 3] * linv);
            int2v o; o[0] = w0; o[1] = w1;
            *(int2v*)(out + obase + d0) = o;
        }
}

// ---------------- launch ----------------
extern "C" void kernel_launch(void* const* d_in, const int* in_sizes, int n_in,
                              void* d_out, int out_size, void* d_ws, size_t ws_size,
                              hipStream_t stream) {
    const float* x      = (const float*)d_in[0];
    const float* w_qkv  = (const float*)d_in[1];
    const float* w_proj = (const float*)d_in[2];
    const int B = 2, T = 2048, C = 2048;
    const int M = B * T;        // 4096
    const int F = 3 * C;        // 6144

    size_t need = ((size_t)M * C + (size_t)F * C + (size_t)M * F) * 2;
    if (ws_size < need) return;
    unsigned short* rX  = (unsigned short*)d_ws;            // x bf16, later attn-out
    unsigned short* rW  = rX + (size_t)M * C;               // w_qkv bf16, later VT + w_proj
    unsigned short* rQ  = rW + (size_t)F * C;               // qkv
    unsigned short* rVT = rW;
    unsigned short* rWp = rW + (size_t)B * 16 * 128 * T;

    cvt2<<<(M * C + F * C) / 1024, 256, 0, stream>>>(x, w_qkv, rX, (M * C) / 4);
    gemm_nt<1><<<dim3(F / 256, M / 128), 512, 0, stream>>>(rX, rW, (void*)rQ, F, C);
    mid_fused<<<4096 + 2048 + 1024, 256, 0, stream>>>(rQ, rVT, w_proj, rWp);
    attn_fused<<<512, 256, 0, stream>>>(rQ, rVT, rX);
    gemm_nt<0><<<dim3(C / 256, M / 128), 512, 0, stream>>>(rX, rWp, d_out, C, C);
}